// Round 18
// baseline (285.721 us; speedup 1.0000x reference)
//
#include <hip/hip_runtime.h>
#include <hip/hip_bf16.h>
#include <hip/hip_fp16.h>
#include <cstdint>
#include <cstddef>

#define NEG_SLOPE 0.2f
#define LOG2E 1.4426950408889634f
#define NBKT 196      // ceil(50000/256) coarse buckets (dst>>8)
#define BCAP 10000    // per-bucket staging capacity (lambda~8163, >20 sigma margin)
#define P1CHUNK 4096
#define P1B 391       // ceil(1.6M/4096)

typedef __attribute__((ext_vector_type(8))) _Float16 f16x8;
typedef __attribute__((ext_vector_type(2))) _Float16 h2;
typedef __attribute__((ext_vector_type(4))) float f32x4;

// ---- fp16 helpers ----
__device__ __forceinline__ unsigned short f2h(float f) {
  _Float16 h = (_Float16)f;
  return __builtin_bit_cast(unsigned short, h);
}
__device__ __forceinline__ unsigned pack2h(float a, float b) {
  return (unsigned)f2h(a) | ((unsigned)f2h(b) << 16);
}

// DPP row-rotate add (16-lane row); CTRL: ror:n = 0x120+n
template <int CTRL>
__device__ __forceinline__ float rr_add(float x) {
  int r = __builtin_amdgcn_update_dpp(0, __float_as_int(x), CTRL, 0xF, 0xF, false);
  return x + __int_as_float(r);
}
__device__ __forceinline__ float row16_sum(float p) {
  p = rr_add<0x121>(p);
  p = rr_add<0x122>(p);
  p = rr_add<0x124>(p);
  p = rr_add<0x128>(p);
  return p;
}

// ---------------- K1: csr_p1 (blocks 0..P1B-1) || prep (rest) ----------------
__device__ __forceinline__ void wt_cvt(const float* __restrict__ Wl,
                                       const float* __restrict__ Wr,
                                       unsigned short* __restrict__ Wt, int K, int C, int idx) {
  const int k = idx / (2 * C);
  const int c = idx - k * 2 * C;
  const float v = (c < C) ? Wl[(size_t)k * C + c] : Wr[(size_t)k * C + (c - C)];
  Wt[(size_t)c * K + k] = f2h(v);
}

__global__ __launch_bounds__(256) void k1_csrp1_prep(
    const int* __restrict__ src, const int* __restrict__ dst,
    int* __restrict__ bcnt, unsigned* __restrict__ stage, int E,
    const float* __restrict__ x,
    const float* __restrict__ W1l, const float* __restrict__ W1r,
    const float* __restrict__ W2l, const float* __restrict__ W2r,
    unsigned short* __restrict__ xhf, unsigned short* __restrict__ Wt1,
    unsigned short* __restrict__ Wt2, long long n8) {
  __shared__ int cnt[NBKT], gbase[NBKT];
  const int b = blockIdx.x;
  const int t = threadIdx.x;
  if (b < P1B) {
    const int base_e = b * P1CHUNK + t;
    int myd[16];
#pragma unroll
    for (int k = 0; k < 16; ++k) {
      const int e = base_e + k * 256;
      myd[k] = (e < E) ? dst[e] : -1;
    }
    for (int i = t; i < NBKT; i += 256) cnt[i] = 0;
    __syncthreads();
#pragma unroll
    for (int k = 0; k < 16; ++k)
      if (myd[k] >= 0) atomicAdd(&cnt[myd[k] >> 8], 1);
    __syncthreads();
    for (int i = t; i < NBKT; i += 256) {
      gbase[i] = cnt[i] ? atomicAdd(&bcnt[i], cnt[i]) : 0;
      cnt[i] = 0;
    }
    __syncthreads();
#pragma unroll
    for (int k = 0; k < 16; ++k) {
      const int d = myd[k];
      if (d >= 0) {
        const int bk = d >> 8;
        const int r = gbase[bk] + atomicAdd(&cnt[bk], 1);
        if (r < BCAP)
          stage[(size_t)bk * BCAP + r] =
              (unsigned)src[base_e + k * 256] | ((unsigned)(d & 255) << 24);
      }
    }
  } else if (b < P1B + 2048) {
    const int lb = b - P1B;
    long long i = (long long)lb * 256 + t;
    const long long s = 2048LL * 256;
    for (; i < n8; i += s) {
      const float4 a = ((const float4*)x)[i * 2];
      const float4 c = ((const float4*)x)[i * 2 + 1];
      ((uint2*)xhf)[i * 2] = make_uint2(pack2h(a.x, a.y), pack2h(a.z, a.w));
      ((uint2*)xhf)[i * 2 + 1] = make_uint2(pack2h(c.x, c.y), pack2h(c.z, c.w));
    }
  } else if (b < P1B + 2048 + 256) {
    wt_cvt(W1l, W1r, Wt1, 128, 256, (b - (P1B + 2048)) * 256 + t);   // 65536 elems
  } else {
    wt_cvt(W2l, W2r, Wt2, 256, 64, (b - (P1B + 2048 + 256)) * 256 + t);  // 32768 elems
  }
}

// ---------------- K2: csr_p2 (blocks 0..NBKT-1) || gemm_mfma l1 (rest) ----------------
template <int K, int NT, int SPLIT>
__device__ __forceinline__ void gemm_body(
    const unsigned short* __restrict__ A, const unsigned short* __restrict__ Wt,
    const float* __restrict__ bl, const float* __restrict__ br,
    unsigned short* __restrict__ Yl, unsigned short* __restrict__ Yr, int bb) {
  constexpr int KS = K / 32;
  constexpr int CW = NT / 4;
  constexpr int NTILES = CW / 16;
  const int wv = threadIdx.x >> 6, lane = threadIdx.x & 63;
  const int n0 = bb * 16;
  const int ar = lane & 15;
  const int kg = lane >> 4;

  f16x8 afrag[KS];
#pragma unroll
  for (int ks = 0; ks < KS; ++ks)
    afrag[ks] = *(const f16x8*)(A + (size_t)(n0 + ar) * K + ks * 32 + kg * 8);

  const int col0w = wv * CW;
#pragma unroll
  for (int nt = 0; nt < NTILES; ++nt) {
    const int c0 = col0w + nt * 16;
    const int ccol = c0 + (lane & 15);
    f32x4 acc = {0.f, 0.f, 0.f, 0.f};
#pragma unroll
    for (int ks = 0; ks < KS; ++ks) {
      const f16x8 bfrag = *(const f16x8*)(Wt + (size_t)ccol * K + ks * 32 + kg * 8);
      acc = __builtin_amdgcn_mfma_f32_16x16x32_f16(afrag[ks], bfrag, acc, 0, 0, 0);
    }
    if (c0 < SPLIT) {
      const float bv = bl[ccol];
#pragma unroll
      for (int j = 0; j < 4; ++j) {
        const int node = n0 + (lane >> 4) * 4 + j;
        Yl[(size_t)node * SPLIT + ccol] = f2h(acc[j] + bv);
      }
    } else {
      const float bv = br[ccol - SPLIT];
#pragma unroll
      for (int j = 0; j < 4; ++j) {
        const int node = n0 + (lane >> 4) * 4 + j;
        Yr[(size_t)node * (NT - SPLIT) + (ccol - SPLIT)] = f2h(acc[j] + bv);
      }
    }
  }
}

__global__ __launch_bounds__(256) void k2_csrp2_gemm1(
    const unsigned* __restrict__ stage, const int* __restrict__ bcnt,
    int* __restrict__ csr_src, int* __restrict__ base, int N, int E,
    const unsigned short* __restrict__ A, const unsigned short* __restrict__ Wt,
    const float* __restrict__ bl, const float* __restrict__ br,
    unsigned short* __restrict__ Yl, unsigned short* __restrict__ Yr) {
  __shared__ int h[256], c[256];
  __shared__ int allb[NBKT];
  __shared__ int ob_s;
  const int b = blockIdx.x;
  const int t = threadIdx.x;
  if (b >= NBKT) {
    gemm_body<128, 512, 256>(A, Wt, bl, br, Yl, Yr, b - NBKT);
    return;
  }
  h[t] = 0;
  for (int i = t; i < NBKT; i += 256) allb[i] = min(bcnt[i], BCAP);
  __syncthreads();
  if (t == 0) {
    int s = 0;
    for (int i = 0; i < b; ++i) s += allb[i];
    ob_s = s;
  }
  __syncthreads();
  const int out_base = ob_s;
  const int cnt = allb[b];
  const unsigned* sp = stage + (size_t)b * BCAP;
  for (int i = t; i < cnt; i += 256) atomicAdd(&h[sp[i] >> 24], 1);
  __syncthreads();
  const int own = h[t];
  for (int off = 1; off < 256; off <<= 1) {
    const int add = (t >= off) ? h[t - off] : 0;
    __syncthreads();
    h[t] += add;
    __syncthreads();
  }
  {
    const int excl = h[t] - own;
    c[t] = excl;
    const int node = b * 256 + t;
    if (node < N) base[node] = out_base + excl;
  }
  if (b == NBKT - 1 && t == 0) base[N] = E;
  __syncthreads();
  for (int i = t; i < cnt; i += 256) {
    const unsigned v = sp[i];
    const int pos = out_base + atomicAdd(&c[v >> 24], 1);
    csr_src[pos] = (int)(v & 0xFFFFFFu);
  }
}

// ---------------- standalone MFMA GEMM (layer 2) ----------------
template <int K, int NT, int SPLIT>
__global__ __launch_bounds__(256) void gemm_mfma(
    const unsigned short* __restrict__ A, const unsigned short* __restrict__ Wt,
    const float* __restrict__ bl, const float* __restrict__ br,
    unsigned short* __restrict__ Yl, unsigned short* __restrict__ Yr) {
  gemm_body<K, NT, SPLIT>(A, Wt, bl, br, Yl, Yr, blockIdx.x);
}

// ---- per-edge fp16 math: native h2 vectors, dot2 accumulate, DPP 16-lane reduce ----
__device__ __forceinline__ void edge_acc_h(uint2 cu, h2 xr01, h2 xr23,
                                           h2 at01, h2 at23, h2 ns,
                                           float& dsum, float4& acc) {
  const h2 a01 = __builtin_bit_cast(h2, cu.x);
  const h2 a23 = __builtin_bit_cast(h2, cu.y);
  const h2 v01 = a01 + xr01;
  const h2 v23 = a23 + xr23;
  const h2 l01 = __builtin_elementwise_max(v01, v01 * ns);
  const h2 l23 = __builtin_elementwise_max(v23, v23 * ns);
  float p = __builtin_amdgcn_fdot2(l01, at01, 0.f, false);
  p = __builtin_amdgcn_fdot2(l23, at23, p, false);
  p = row16_sum(p);
  p = __builtin_amdgcn_exp2f(p);
  dsum += p;
  acc.x = fmaf(p, (float)a01.x, acc.x);
  acc.y = fmaf(p, (float)a01.y, acc.y);
  acc.z = fmaf(p, (float)a23.x, acc.z);
  acc.w = fmaf(p, (float)a23.y, acc.w);
}

// ---------------- layer 1 fused: wave/node, fp16x4/lane, 4-deep prefetch ----------------
__global__ __launch_bounds__(256) void node_l1_fused(
    const unsigned short* __restrict__ xlh, const unsigned short* __restrict__ xrh,
    const int* __restrict__ csr_src, const int* __restrict__ base,
    const float* __restrict__ att, const float* __restrict__ bias,
    unsigned short* __restrict__ outh, int N) {
  const int wv = threadIdx.x >> 6, lane = threadIdx.x & 63;
  const int n = blockIdx.x * 4 + wv;
  if (n >= N) return;
  const int beg = __builtin_amdgcn_readfirstlane(base[n]);
  const int deg = __builtin_amdgcn_readfirstlane(base[n + 1]) - beg;
  const uint2 xru = ((const uint2*)xrh)[(size_t)n * 64 + lane];
  const h2 xr01 = __builtin_bit_cast(h2, xru.x);
  const h2 xr23 = __builtin_bit_cast(h2, xru.y);
  const float4 a4 = ((const float4*)att)[lane];
  h2 at01, at23, ns;
  at01.x = (_Float16)(a4.x * LOG2E); at01.y = (_Float16)(a4.y * LOG2E);
  at23.x = (_Float16)(a4.z * LOG2E); at23.y = (_Float16)(a4.w * LOG2E);
  ns.x = (_Float16)NEG_SLOPE; ns.y = (_Float16)NEG_SLOPE;

  float dsum = 0.f;
  float4 acc = make_float4(0.f, 0.f, 0.f, 0.f);

  if (deg > 0) {
    const int dm1 = deg - 1;
    const char* XLc = (const char*)xlh;     // row = 512 B
    const unsigned lb = (unsigned)lane << 3;
    int s0 = csr_src[beg];
    int s1 = csr_src[beg + (1 < dm1 ? 1 : dm1)];
    int s2 = csr_src[beg + (2 < dm1 ? 2 : dm1)];
    int s3 = csr_src[beg + (3 < dm1 ? 3 : dm1)];
    uint2 r0 = *(const uint2*)(XLc + (((unsigned)s0 << 9) | lb));
    uint2 r1 = *(const uint2*)(XLc + (((unsigned)s1 << 9) | lb));
    uint2 r2 = *(const uint2*)(XLc + (((unsigned)s2 << 9) | lb));
    uint2 r3 = *(const uint2*)(XLc + (((unsigned)s3 << 9) | lb));
    s0 = csr_src[beg + (4 < dm1 ? 4 : dm1)];
    s1 = csr_src[beg + (5 < dm1 ? 5 : dm1)];
    s2 = csr_src[beg + (6 < dm1 ? 6 : dm1)];
    s3 = csr_src[beg + (7 < dm1 ? 7 : dm1)];
    for (int i = 0; i < deg; i += 4) {
      const uint2 c0 = r0, c1 = r1, c2 = r2, c3 = r3;
      r0 = *(const uint2*)(XLc + (((unsigned)s0 << 9) | lb));
      r1 = *(const uint2*)(XLc + (((unsigned)s1 << 9) | lb));
      r2 = *(const uint2*)(XLc + (((unsigned)s2 << 9) | lb));
      r3 = *(const uint2*)(XLc + (((unsigned)s3 << 9) | lb));
      const int j0 = i + 8 < dm1 ? i + 8 : dm1;
      const int j1 = i + 9 < dm1 ? i + 9 : dm1;
      const int j2 = i + 10 < dm1 ? i + 10 : dm1;
      const int j3 = i + 11 < dm1 ? i + 11 : dm1;
      s0 = csr_src[beg + j0];
      s1 = csr_src[beg + j1];
      s2 = csr_src[beg + j2];
      s3 = csr_src[beg + j3];
      edge_acc_h(c0, xr01, xr23, at01, at23, ns, dsum, acc);
      if (i + 1 <= dm1) edge_acc_h(c1, xr01, xr23, at01, at23, ns, dsum, acc);
      if (i + 2 <= dm1) edge_acc_h(c2, xr01, xr23, at01, at23, ns, dsum, acc);
      if (i + 3 <= dm1) edge_acc_h(c3, xr01, xr23, at01, at23, ns, dsum, acc);
    }
  }
  const float inv = (deg > 0) ? 1.0f / dsum : 0.f;
  const float4 b4 = ((const float4*)bias)[lane];
  float4 o;
  o.x = fmaf(acc.x, inv, b4.x); o.x = o.x > 0.f ? o.x : expm1f(o.x);
  o.y = fmaf(acc.y, inv, b4.y); o.y = o.y > 0.f ? o.y : expm1f(o.y);
  o.z = fmaf(acc.z, inv, b4.z); o.z = o.z > 0.f ? o.z : expm1f(o.z);
  o.w = fmaf(acc.w, inv, b4.w); o.w = o.w > 0.f ? o.w : expm1f(o.w);
  ((uint2*)outh)[(size_t)n * 64 + lane] = make_uint2(pack2h(o.x, o.y), pack2h(o.z, o.w));
}

// ---------------- layer 2 fused: 16-lane group/node, 2-deep prefetch, DPP reduces ----------------
__global__ __launch_bounds__(256) void node_l2_fused(
    const unsigned short* __restrict__ xlh, const unsigned short* __restrict__ xrh,
    const int* __restrict__ csr_src, const int* __restrict__ base,
    const float* __restrict__ att, const float* __restrict__ bias,
    const float* __restrict__ Wro, const float* __restrict__ bro,
    float* __restrict__ out, int N) {
  const int gl = threadIdx.x & 15;
  const int n = blockIdx.x * 16 + (threadIdx.x >> 4);
  const int gbase = (threadIdx.x & 63) & 48;
  if (n >= N) return;
  const int beg = base[n];
  const int deg = base[n + 1] - beg;
  const uint2 xru = ((const uint2*)xrh)[(size_t)n * 16 + gl];
  const h2 xr01 = __builtin_bit_cast(h2, xru.x);
  const h2 xr23 = __builtin_bit_cast(h2, xru.y);
  const float4 a4 = ((const float4*)att)[gl];
  h2 at01, at23, ns;
  at01.x = (_Float16)(a4.x * LOG2E); at01.y = (_Float16)(a4.y * LOG2E);
  at23.x = (_Float16)(a4.z * LOG2E); at23.y = (_Float16)(a4.w * LOG2E);
  ns.x = (_Float16)NEG_SLOPE; ns.y = (_Float16)NEG_SLOPE;
  const char* XLc = (const char*)xlh;       // row = 128 B
  const unsigned lb = (unsigned)gl << 3;

  float dsum = 0.f;
  float4 acc = make_float4(0.f, 0.f, 0.f, 0.f);

  for (int chunk = 0; chunk < deg; chunk += 16) {
    const int cnt = min(16, deg - chunk);
    const int cm1 = cnt - 1;
    const int si = (gl < cnt) ? csr_src[beg + chunk + gl] : 0;
    int sA = __shfl(si, gbase);
    int sB = __shfl(si, gbase + (1 < cm1 ? 1 : cm1));
    uint2 nx0 = *(const uint2*)(XLc + (((unsigned)sA << 7) | lb));
    uint2 nx1 = *(const uint2*)(XLc + (((unsigned)sB << 7) | lb));
    for (int j = 0; j < cnt; ++j) {
      const uint2 cj = nx0;
      nx0 = nx1;
      const int jn = j + 2 < cm1 ? j + 2 : cm1;
      const int s2 = __shfl(si, gbase + jn);
      nx1 = *(const uint2*)(XLc + (((unsigned)s2 << 7) | lb));
      edge_acc_h(cj, xr01, xr23, at01, at23, ns, dsum, acc);
    }
  }
  const float inv = (deg > 0) ? 1.0f / dsum : 0.f;
  const float4 b4 = ((const float4*)bias)[gl];
  float ox = fmaf(acc.x, inv, b4.x); ox = ox > 0.f ? ox : expm1f(ox);
  float oy = fmaf(acc.y, inv, b4.y); oy = oy > 0.f ? oy : expm1f(oy);
  float oz = fmaf(acc.z, inv, b4.z); oz = oz > 0.f ? oz : expm1f(oz);
  float ow = fmaf(acc.w, inv, b4.w); ow = ow > 0.f ? ow : expm1f(ow);
  const float4 w4 = ((const float4*)Wro)[gl];
  float r = ox * w4.x + oy * w4.y + oz * w4.z + ow * w4.w;
  r = row16_sum(r);
  if (gl == 0) out[n] = r + bro[0];
}

extern "C" void kernel_launch(void* const* d_in, const int* in_sizes, int n_in,
                              void* d_out, int out_size, void* d_ws, size_t ws_size,
                              hipStream_t stream) {
  const float* x     = (const float*)d_in[0];
  const int*   ei    = (const int*)d_in[1];
  const float* W1l   = (const float*)d_in[2];
  const float* b1l   = (const float*)d_in[3];
  const float* W1r   = (const float*)d_in[4];
  const float* b1r   = (const float*)d_in[5];
  const float* att1  = (const float*)d_in[6];
  const float* bias1 = (const float*)d_in[7];
  const float* W2l   = (const float*)d_in[8];
  const float* b2l   = (const float*)d_in[9];
  const float* W2r   = (const float*)d_in[10];
  const float* b2r   = (const float*)d_in[11];
  const float* att2  = (const float*)d_in[12];
  const float* bias2 = (const float*)d_in[13];
  const float* Wro   = (const float*)d_in[14];
  const float* bro   = (const float*)d_in[15];

  const int N = in_sizes[0] / 128;  // 50000
  const int E = in_sizes[1] / 2;
  const int* src = ei;
  const int* dst = ei + E;

  // ---- workspace layout (float-unit offsets) ----
  float* ws = (float*)d_ws;
  unsigned short* xhf  = (unsigned short*)ws;                      // N*128 fp16
  unsigned short* xl1h = (unsigned short*)(ws + (size_t)64 * N);   // N*256 fp16
  unsigned short* xr1h = (unsigned short*)(ws + (size_t)192 * N);  // N*256 fp16
  unsigned short* h1h  = (unsigned short*)(ws + (size_t)320 * N);  // N*256 fp16
  int* csr_src = (int*)(ws + (size_t)448 * N);                     // [E]
  int* base    = csr_src + E;                                      // [N+1]
  int* bcnt    = base + N + 1;                                     // [NBKT]
  unsigned* stage = (unsigned*)(bcnt + NBKT);                      // [NBKT*BCAP]
  unsigned short* Wt1 = (unsigned short*)(stage + (size_t)NBKT * BCAP);  // 512*128 fp16
  unsigned short* Wt2 = Wt1 + 512 * 128;                           // 128*256 fp16
  unsigned short* xl2h = xhf;                                      // N*64 fp16 (alias)
  unsigned short* xr2h = xl1h;                                     // N*64 fp16 (alias)

  // ---- K0: zero bcnt ----
  (void)hipMemsetAsync((void*)bcnt, 0, NBKT * sizeof(int), stream);

  // ---- K1: csr_p1 || prep ----
  k1_csrp1_prep<<<dim3(P1B + 2048 + 256 + 128), dim3(256), 0, stream>>>(
      src, dst, bcnt, stage, E, x, W1l, W1r, W2l, W2r, xhf, Wt1, Wt2,
      (long long)N * 128 / 8);

  // ---- K2: csr_p2 || gemm l1 ----
  k2_csrp2_gemm1<<<dim3(NBKT + N / 16), dim3(256), 0, stream>>>(
      stage, bcnt, csr_src, base, N, E, xhf, Wt1, b1l, b1r, xl1h, xr1h);

  // ---- node l1 ----
  node_l1_fused<<<dim3((N + 3) / 4), dim3(256), 0, stream>>>(xl1h, xr1h, csr_src, base,
                                                             att1, bias1, h1h, N);

  // ---- gemm l2 ----
  gemm_mfma<256, 128, 64><<<dim3(N / 16), dim3(256), 0, stream>>>(h1h, Wt2, b2l, b2r,
                                                                  xl2h, xr2h);

  // ---- node l2 + readout ----
  node_l2_fused<<<dim3((N + 15) / 16), dim3(256), 0, stream>>>(xl2h, xr2h, csr_src, base,
                                                               att2, bias2, Wro, bro,
                                                               (float*)d_out, N);
}